// Round 1
// baseline (229.698 us; speedup 1.0000x reference)
//
#include <hip/hip_runtime.h>

#define NCAMS 5
#define BB 4
#define JJ 15
#define HH 128
#define WW 240
#define CXX 80
#define CYY 80
#define CZZ 20
#define NBINS 128000            // 80*80*20
#define HW (HH*WW)              // 30720
#define CUBES_ELEMS (BB*JJ*NBINS) // 7,680,000
#define BLOCK 256
#define BLOCKS_PER_B (NBINS / BLOCK) // 500

__global__ __launch_bounds__(BLOCK) void project_kernel(
    const float* __restrict__ hm,   // (5,4,15,128,240)
    const float* __restrict__ R,    // (5,4,3,3)
    const float* __restrict__ T,    // (5,4,3)
    const float* __restrict__ f,    // (5,4,2)
    const float* __restrict__ c,    // (5,4,2)
    const float* __restrict__ k,    // (5,4,3)
    const float* __restrict__ p,    // (5,4,2)
    const float* __restrict__ wh,   // (5,4,2)
    const float* __restrict__ gc,   // (4,3)
    const float* __restrict__ gs,   // (3,)
    float* __restrict__ out)        // cubes (4,15,128000) then grids (4,128000,3)
{
    // blockIdx.x = b * BLOCKS_PER_B + tile  -> b uniform per block (s_loads for cam params)
    const int b = blockIdx.x / BLOCKS_PER_B;
    const int m = (blockIdx.x % BLOCKS_PER_B) * BLOCK + threadIdx.x;

    // voxel coords: m = i*(80*20) + jy*20 + kz  (meshgrid 'ij', C-order ravel)
    const int i   = m / (CYY * CZZ);
    const int rem = m - i * (CYY * CZZ);
    const int jy  = rem / CZZ;
    const int kz  = rem - jy * CZZ;

    const float gs0 = gs[0], gs1 = gs[1], gs2 = gs[2];
    const float gx = -0.5f * gs0 + (float)i  * (gs0 / (float)(CXX - 1)) + gc[b * 3 + 0];
    const float gy = -0.5f * gs1 + (float)jy * (gs1 / (float)(CYY - 1)) + gc[b * 3 + 1];
    const float gz = -0.5f * gs2 + (float)kz * (gs2 / (float)(CZZ - 1)) + gc[b * 3 + 2];

    // grids output: out[CUBES_ELEMS + (b*NBINS + m)*3 + {0,1,2}]
    float* gout = out + CUBES_ELEMS + ((size_t)b * NBINS + m) * 3;
    gout[0] = gx; gout[1] = gy; gout[2] = gz;

    float num[JJ];
#pragma unroll
    for (int j = 0; j < JJ; ++j) num[j] = 0.f;
    float den = 0.f;

    for (int n = 0; n < NCAMS; ++n) {
        const int pb = n * BB + b;                 // wave-uniform
        const float* Rp = R + pb * 9;

        const float dx = gx - T[pb * 3 + 0];
        const float dy = gy - T[pb * 3 + 1];
        const float dz = gz - T[pb * 3 + 2];

        // xcam_i = sum_j R[i][j] * d[j]
        const float xc = Rp[0] * dx + Rp[1] * dy + Rp[2] * dz;
        const float yc = Rp[3] * dx + Rp[4] * dy + Rp[5] * dz;
        const float zc = Rp[6] * dx + Rp[7] * dy + Rp[8] * dz;

        const float y0 = xc / zc;
        const float y1 = yc / zc;
        const float r2 = y0 * y0 + y1 * y1;

        const float k0 = k[pb * 3 + 0], k1 = k[pb * 3 + 1], k2 = k[pb * 3 + 2];
        const float radial = 1.f + k0 * r2 + k1 * r2 * r2 + k2 * r2 * r2 * r2;
        const float p0v = p[pb * 2 + 0], p1v = p[pb * 2 + 1];
        const float tanv = p0v * y1 + p1v * y0;
        const float s = radial + tanv;
        const float xy0 = y0 * s + r2 * p1v;
        const float xy1 = y1 * s + r2 * p0v;

        const float pixx = xy0 * f[pb * 2 + 0] + c[pb * 2 + 0];
        const float pixy = xy1 * f[pb * 2 + 1] + c[pb * 2 + 1];

        const float wv = wh[pb * 2 + 0], hv = wh[pb * 2 + 1];
        const bool inb = (pixx >= 0.f) & (pixy >= 0.f) & (pixx < wv) & (pixy < hv);
        if (!inb) continue;   // bound==0 -> contributes nothing to num or den
        den += 1.f;

        const float maxwh = fmaxf(wv, hv);
        float pcx = fminf(fmaxf(pixx, -1.f), maxwh);
        float pcy = fminf(fmaxf(pixy, -1.f), maxwh);
        float nx = pcx / (wv - 1.f) * 2.f - 1.f;
        float ny = pcy / (hv - 1.f) * 2.f - 1.f;
        nx = fminf(fmaxf(nx, -1.1f), 1.1f);
        ny = fminf(fmaxf(ny, -1.1f), 1.1f);

        const float ix = (nx + 1.f) * 0.5f * (float)(WW - 1);
        const float iy = (ny + 1.f) * 0.5f * (float)(HH - 1);
        const float x0f = floorf(ix), y0f = floorf(iy);
        const float x1f = x0f + 1.f, y1f = y0f + 1.f;
        const float wx1 = ix - x0f, wx0 = 1.f - wx1;
        const float wy1 = iy - y0f, wy0 = 1.f - wy1;

        const float vx0 = (x0f >= 0.f && x0f < (float)WW) ? 1.f : 0.f;
        const float vx1 = (x1f >= 0.f && x1f < (float)WW) ? 1.f : 0.f;
        const float vy0 = (y0f >= 0.f && y0f < (float)HH) ? 1.f : 0.f;
        const float vy1 = (y1f >= 0.f && y1f < (float)HH) ? 1.f : 0.f;

        const float w00 = wx0 * wy0 * vx0 * vy0;
        const float w10 = wx1 * wy0 * vx1 * vy0;
        const float w01 = wx0 * wy1 * vx0 * vy1;
        const float w11 = wx1 * wy1 * vx1 * vy1;

        const int xi0 = min(max((int)x0f, 0), WW - 1);
        const int xi1 = min(max((int)x1f, 0), WW - 1);
        const int yi0 = min(max((int)y0f, 0), HH - 1);
        const int yi1 = min(max((int)y1f, 0), HH - 1);

        const int o00 = yi0 * WW + xi0;
        const int o10 = yi0 * WW + xi1;
        const int o01 = yi1 * WW + xi0;
        const int o11 = yi1 * WW + xi1;

        const float* img = hm + (size_t)pb * JJ * HW;
#pragma unroll
        for (int j = 0; j < JJ; ++j) {
            const float* pj = img + j * HW;
            num[j] += pj[o00] * w00 + pj[o10] * w10 + pj[o01] * w01 + pj[o11] * w11;
        }
    }

    const float inv = 1.f / (den + 1e-6f);
    float* cout = out + (size_t)b * JJ * NBINS + m;
#pragma unroll
    for (int j = 0; j < JJ; ++j) {
        float v = num[j] * inv;
        v = (v != v) ? 0.f : v;          // isnan -> 0
        v = fminf(fmaxf(v, 0.f), 1.f);   // clip 0..1
        cout[(size_t)j * NBINS] = v;
    }
}

extern "C" void kernel_launch(void* const* d_in, const int* in_sizes, int n_in,
                              void* d_out, int out_size, void* d_ws, size_t ws_size,
                              hipStream_t stream) {
    const float* hm = (const float*)d_in[0];
    const float* R  = (const float*)d_in[1];
    const float* T  = (const float*)d_in[2];
    const float* f  = (const float*)d_in[3];
    const float* c  = (const float*)d_in[4];
    const float* k  = (const float*)d_in[5];
    const float* p  = (const float*)d_in[6];
    const float* wh = (const float*)d_in[7];
    const float* gc = (const float*)d_in[8];
    const float* gs = (const float*)d_in[9];
    float* out = (float*)d_out;

    project_kernel<<<dim3(BB * BLOCKS_PER_B), dim3(BLOCK), 0, stream>>>(
        hm, R, T, f, c, k, p, wh, gc, gs, out);
}

// Round 2
// 154.754 us; speedup vs baseline: 1.4843x; 1.4843x over previous
//
#include <hip/hip_runtime.h>

#define NCAMS 5
#define BB 4
#define JJ 15
#define JP 16                    // joints padded to 16 (one 64B line per pixel)
#define HH 128
#define WW 240
#define CXX 80
#define CYY 80
#define CZZ 20
#define NBINS 128000             // 80*80*20
#define HW (HH*WW)               // 30720
#define CUBES_ELEMS (BB*JJ*NBINS) // 7,680,000
#define BLOCK 256
#define BLOCKS_PER_B (NBINS / BLOCK) // 500
#define WS_NEEDED ((size_t)NCAMS * BB * HW * JP * sizeof(float)) // 39,321,600 B

// ---------------------------------------------------------------------------
// Pass 1: transpose (n,b,j,h,w) -> (n,b,h,w,jp) with jp=16 (j=15 zero pad).
// Thread t covers one float4 of the output: t = (nb*HW + pix)*4 + q.
// Writes: perfectly coalesced float4 (1 KB/wave). Reads: per (q,s) lanes span
// 16 consecutive pix -> 64B segments.
// ---------------------------------------------------------------------------
__global__ __launch_bounds__(BLOCK) void transpose_kernel(
    const float* __restrict__ hm, float4* __restrict__ tz)
{
    const int t = blockIdx.x * BLOCK + threadIdx.x;   // < 20*HW*4 = 2,457,600
    const int q = t & 3;
    const int pixnb = t >> 2;
    const int nb = pixnb / HW;
    const int pix = pixnb - nb * HW;
    const float* src = hm + (size_t)nb * JJ * HW + pix;
    const int j0 = q * 4;
    float4 v;
    v.x = src[(j0 + 0) * HW];
    v.y = src[(j0 + 1) * HW];
    v.z = src[(j0 + 2) * HW];
    v.w = (j0 + 3 < JJ) ? src[(j0 + 3) * HW] : 0.f;
    tz[t] = v;
}

__device__ __forceinline__ void fma4(float4& acc, const float4 v, const float w) {
    acc.x = fmaf(v.x, w, acc.x);
    acc.y = fmaf(v.y, w, acc.y);
    acc.z = fmaf(v.z, w, acc.z);
    acc.w = fmaf(v.w, w, acc.w);
}

// ---------------------------------------------------------------------------
// Pass 2: projection + bilinear gather from transposed layout.
// One thread per (b, voxel); 5 cams; per in-bounds cam: 4 corners x 4 float4
// loads (each corner = one fully-used 64B line).
// ---------------------------------------------------------------------------
__global__ __launch_bounds__(BLOCK) void project_kernel_t(
    const float4* __restrict__ tz,  // (5,4,HW,16) floats as float4[...,4]
    const float* __restrict__ R, const float* __restrict__ T,
    const float* __restrict__ f, const float* __restrict__ c,
    const float* __restrict__ k, const float* __restrict__ p,
    const float* __restrict__ wh,
    const float* __restrict__ gc, const float* __restrict__ gs,
    float* __restrict__ out)
{
    const int b = blockIdx.x / BLOCKS_PER_B;
    const int m = (blockIdx.x % BLOCKS_PER_B) * BLOCK + threadIdx.x;

    const int i   = m / (CYY * CZZ);
    const int rem = m - i * (CYY * CZZ);
    const int jy  = rem / CZZ;
    const int kz  = rem - jy * CZZ;

    const float gs0 = gs[0], gs1 = gs[1], gs2 = gs[2];
    const float gx = -0.5f * gs0 + (float)i  * (gs0 / (float)(CXX - 1)) + gc[b * 3 + 0];
    const float gy = -0.5f * gs1 + (float)jy * (gs1 / (float)(CYY - 1)) + gc[b * 3 + 1];
    const float gz = -0.5f * gs2 + (float)kz * (gs2 / (float)(CZZ - 1)) + gc[b * 3 + 2];

    float* gout = out + CUBES_ELEMS + ((size_t)b * NBINS + m) * 3;
    gout[0] = gx; gout[1] = gy; gout[2] = gz;

    float4 acc0 = {0,0,0,0}, acc1 = {0,0,0,0}, acc2 = {0,0,0,0}, acc3 = {0,0,0,0};
    float den = 0.f;

    for (int n = 0; n < NCAMS; ++n) {
        const int pb = n * BB + b;                 // wave-uniform
        const float* Rp = R + pb * 9;

        const float dx = gx - T[pb * 3 + 0];
        const float dy = gy - T[pb * 3 + 1];
        const float dz = gz - T[pb * 3 + 2];

        const float xc = Rp[0] * dx + Rp[1] * dy + Rp[2] * dz;
        const float yc = Rp[3] * dx + Rp[4] * dy + Rp[5] * dz;
        const float zc = Rp[6] * dx + Rp[7] * dy + Rp[8] * dz;

        const float y0 = xc / zc;
        const float y1 = yc / zc;
        const float r2 = y0 * y0 + y1 * y1;

        const float k0 = k[pb * 3 + 0], k1 = k[pb * 3 + 1], k2 = k[pb * 3 + 2];
        const float radial = 1.f + k0 * r2 + k1 * r2 * r2 + k2 * r2 * r2 * r2;
        const float p0v = p[pb * 2 + 0], p1v = p[pb * 2 + 1];
        const float tanv = p0v * y1 + p1v * y0;
        const float s = radial + tanv;
        const float xy0 = y0 * s + r2 * p1v;
        const float xy1 = y1 * s + r2 * p0v;

        const float pixx = xy0 * f[pb * 2 + 0] + c[pb * 2 + 0];
        const float pixy = xy1 * f[pb * 2 + 1] + c[pb * 2 + 1];

        const float wv = wh[pb * 2 + 0], hv = wh[pb * 2 + 1];
        const bool inb = (pixx >= 0.f) & (pixy >= 0.f) & (pixx < wv) & (pixy < hv);
        if (!inb) continue;
        den += 1.f;

        const float maxwh = fmaxf(wv, hv);
        float pcx = fminf(fmaxf(pixx, -1.f), maxwh);
        float pcy = fminf(fmaxf(pixy, -1.f), maxwh);
        float nx = pcx / (wv - 1.f) * 2.f - 1.f;
        float ny = pcy / (hv - 1.f) * 2.f - 1.f;
        nx = fminf(fmaxf(nx, -1.1f), 1.1f);
        ny = fminf(fmaxf(ny, -1.1f), 1.1f);

        const float ix = (nx + 1.f) * 0.5f * (float)(WW - 1);
        const float iy = (ny + 1.f) * 0.5f * (float)(HH - 1);
        const float x0f = floorf(ix), y0f = floorf(iy);
        const float x1f = x0f + 1.f, y1f = y0f + 1.f;
        const float wx1 = ix - x0f, wx0 = 1.f - wx1;
        const float wy1 = iy - y0f, wy0 = 1.f - wy1;

        const float vx0 = (x0f >= 0.f && x0f < (float)WW) ? 1.f : 0.f;
        const float vx1 = (x1f >= 0.f && x1f < (float)WW) ? 1.f : 0.f;
        const float vy0 = (y0f >= 0.f && y0f < (float)HH) ? 1.f : 0.f;
        const float vy1 = (y1f >= 0.f && y1f < (float)HH) ? 1.f : 0.f;

        const float w00 = wx0 * wy0 * vx0 * vy0;
        const float w10 = wx1 * wy0 * vx1 * vy0;
        const float w01 = wx0 * wy1 * vx0 * vy1;
        const float w11 = wx1 * wy1 * vx1 * vy1;

        const int xi0 = min(max((int)x0f, 0), WW - 1);
        const int xi1 = min(max((int)x1f, 0), WW - 1);
        const int yi0 = min(max((int)y0f, 0), HH - 1);
        const int yi1 = min(max((int)y1f, 0), HH - 1);

        const float4* img4 = tz + (size_t)pb * HW * 4;
        const float4* p00 = img4 + (yi0 * WW + xi0) * 4;
        const float4* p10 = img4 + (yi0 * WW + xi1) * 4;
        const float4* p01 = img4 + (yi1 * WW + xi0) * 4;
        const float4* p11 = img4 + (yi1 * WW + xi1) * 4;

        // issue all 16 loads, then accumulate (max memory-level parallelism)
        const float4 a00 = p00[0], a01 = p00[1], a02 = p00[2], a03 = p00[3];
        const float4 b00 = p10[0], b01 = p10[1], b02 = p10[2], b03 = p10[3];
        const float4 c00 = p01[0], c01 = p01[1], c02 = p01[2], c03 = p01[3];
        const float4 d00 = p11[0], d01 = p11[1], d02 = p11[2], d03 = p11[3];

        fma4(acc0, a00, w00); fma4(acc0, b00, w10); fma4(acc0, c00, w01); fma4(acc0, d00, w11);
        fma4(acc1, a01, w00); fma4(acc1, b01, w10); fma4(acc1, c01, w01); fma4(acc1, d01, w11);
        fma4(acc2, a02, w00); fma4(acc2, b02, w10); fma4(acc2, c02, w01); fma4(acc2, d02, w11);
        fma4(acc3, a03, w00); fma4(acc3, b03, w10); fma4(acc3, c03, w01); fma4(acc3, d03, w11);
    }

    const float inv = 1.f / (den + 1e-6f);
    float num[JP];
    num[0]=acc0.x; num[1]=acc0.y; num[2]=acc0.z; num[3]=acc0.w;
    num[4]=acc1.x; num[5]=acc1.y; num[6]=acc1.z; num[7]=acc1.w;
    num[8]=acc2.x; num[9]=acc2.y; num[10]=acc2.z; num[11]=acc2.w;
    num[12]=acc3.x; num[13]=acc3.y; num[14]=acc3.z; num[15]=acc3.w;

    float* cout = out + (size_t)b * JJ * NBINS + m;
#pragma unroll
    for (int j = 0; j < JJ; ++j) {
        float v = num[j] * inv;
        v = (v != v) ? 0.f : v;
        v = fminf(fmaxf(v, 0.f), 1.f);
        cout[(size_t)j * NBINS] = v;
    }
}

// ---------------------------------------------------------------------------
// Fallback (R1 kernel): used only if ws_size < WS_NEEDED.
// ---------------------------------------------------------------------------
__global__ __launch_bounds__(BLOCK) void project_kernel_fb(
    const float* __restrict__ hm,
    const float* __restrict__ R, const float* __restrict__ T,
    const float* __restrict__ f, const float* __restrict__ c,
    const float* __restrict__ k, const float* __restrict__ p,
    const float* __restrict__ wh,
    const float* __restrict__ gc, const float* __restrict__ gs,
    float* __restrict__ out)
{
    const int b = blockIdx.x / BLOCKS_PER_B;
    const int m = (blockIdx.x % BLOCKS_PER_B) * BLOCK + threadIdx.x;
    const int i   = m / (CYY * CZZ);
    const int rem = m - i * (CYY * CZZ);
    const int jy  = rem / CZZ;
    const int kz  = rem - jy * CZZ;

    const float gs0 = gs[0], gs1 = gs[1], gs2 = gs[2];
    const float gx = -0.5f * gs0 + (float)i  * (gs0 / (float)(CXX - 1)) + gc[b * 3 + 0];
    const float gy = -0.5f * gs1 + (float)jy * (gs1 / (float)(CYY - 1)) + gc[b * 3 + 1];
    const float gz = -0.5f * gs2 + (float)kz * (gs2 / (float)(CZZ - 1)) + gc[b * 3 + 2];

    float* gout = out + CUBES_ELEMS + ((size_t)b * NBINS + m) * 3;
    gout[0] = gx; gout[1] = gy; gout[2] = gz;

    float num[JJ];
#pragma unroll
    for (int j = 0; j < JJ; ++j) num[j] = 0.f;
    float den = 0.f;

    for (int n = 0; n < NCAMS; ++n) {
        const int pb = n * BB + b;
        const float* Rp = R + pb * 9;
        const float dx = gx - T[pb * 3 + 0];
        const float dy = gy - T[pb * 3 + 1];
        const float dz = gz - T[pb * 3 + 2];
        const float xc = Rp[0] * dx + Rp[1] * dy + Rp[2] * dz;
        const float yc = Rp[3] * dx + Rp[4] * dy + Rp[5] * dz;
        const float zc = Rp[6] * dx + Rp[7] * dy + Rp[8] * dz;
        const float y0 = xc / zc;
        const float y1 = yc / zc;
        const float r2 = y0 * y0 + y1 * y1;
        const float k0 = k[pb * 3 + 0], k1 = k[pb * 3 + 1], k2 = k[pb * 3 + 2];
        const float radial = 1.f + k0 * r2 + k1 * r2 * r2 + k2 * r2 * r2 * r2;
        const float p0v = p[pb * 2 + 0], p1v = p[pb * 2 + 1];
        const float s = radial + p0v * y1 + p1v * y0;
        const float xy0 = y0 * s + r2 * p1v;
        const float xy1 = y1 * s + r2 * p0v;
        const float pixx = xy0 * f[pb * 2 + 0] + c[pb * 2 + 0];
        const float pixy = xy1 * f[pb * 2 + 1] + c[pb * 2 + 1];
        const float wv = wh[pb * 2 + 0], hv = wh[pb * 2 + 1];
        const bool inb = (pixx >= 0.f) & (pixy >= 0.f) & (pixx < wv) & (pixy < hv);
        if (!inb) continue;
        den += 1.f;
        const float maxwh = fmaxf(wv, hv);
        float pcx = fminf(fmaxf(pixx, -1.f), maxwh);
        float pcy = fminf(fmaxf(pixy, -1.f), maxwh);
        float nx = fminf(fmaxf(pcx / (wv - 1.f) * 2.f - 1.f, -1.1f), 1.1f);
        float ny = fminf(fmaxf(pcy / (hv - 1.f) * 2.f - 1.f, -1.1f), 1.1f);
        const float ix = (nx + 1.f) * 0.5f * (float)(WW - 1);
        const float iy = (ny + 1.f) * 0.5f * (float)(HH - 1);
        const float x0f = floorf(ix), y0f = floorf(iy);
        const float x1f = x0f + 1.f, y1f = y0f + 1.f;
        const float wx1 = ix - x0f, wx0 = 1.f - wx1;
        const float wy1 = iy - y0f, wy0 = 1.f - wy1;
        const float vx0 = (x0f >= 0.f && x0f < (float)WW) ? 1.f : 0.f;
        const float vx1 = (x1f >= 0.f && x1f < (float)WW) ? 1.f : 0.f;
        const float vy0 = (y0f >= 0.f && y0f < (float)HH) ? 1.f : 0.f;
        const float vy1 = (y1f >= 0.f && y1f < (float)HH) ? 1.f : 0.f;
        const float w00 = wx0 * wy0 * vx0 * vy0;
        const float w10 = wx1 * wy0 * vx1 * vy0;
        const float w01 = wx0 * wy1 * vx0 * vy1;
        const float w11 = wx1 * wy1 * vx1 * vy1;
        const int xi0 = min(max((int)x0f, 0), WW - 1);
        const int xi1 = min(max((int)x1f, 0), WW - 1);
        const int yi0 = min(max((int)y0f, 0), HH - 1);
        const int yi1 = min(max((int)y1f, 0), HH - 1);
        const int o00 = yi0 * WW + xi0;
        const int o10 = yi0 * WW + xi1;
        const int o01 = yi1 * WW + xi0;
        const int o11 = yi1 * WW + xi1;
        const float* img = hm + (size_t)pb * JJ * HW;
#pragma unroll
        for (int j = 0; j < JJ; ++j) {
            const float* pj = img + j * HW;
            num[j] += pj[o00] * w00 + pj[o10] * w10 + pj[o01] * w01 + pj[o11] * w11;
        }
    }

    const float inv = 1.f / (den + 1e-6f);
    float* cout = out + (size_t)b * JJ * NBINS + m;
#pragma unroll
    for (int j = 0; j < JJ; ++j) {
        float v = num[j] * inv;
        v = (v != v) ? 0.f : v;
        v = fminf(fmaxf(v, 0.f), 1.f);
        cout[(size_t)j * NBINS] = v;
    }
}

extern "C" void kernel_launch(void* const* d_in, const int* in_sizes, int n_in,
                              void* d_out, int out_size, void* d_ws, size_t ws_size,
                              hipStream_t stream) {
    const float* hm = (const float*)d_in[0];
    const float* R  = (const float*)d_in[1];
    const float* T  = (const float*)d_in[2];
    const float* f  = (const float*)d_in[3];
    const float* c  = (const float*)d_in[4];
    const float* k  = (const float*)d_in[5];
    const float* p  = (const float*)d_in[6];
    const float* wh = (const float*)d_in[7];
    const float* gc = (const float*)d_in[8];
    const float* gs = (const float*)d_in[9];
    float* out = (float*)d_out;

    if (ws_size >= WS_NEEDED) {
        float4* tz = (float4*)d_ws;
        // 20*HW*4 float4s / 256 threads = 9600 blocks
        transpose_kernel<<<dim3(NCAMS * BB * HW * 4 / BLOCK), dim3(BLOCK), 0, stream>>>(
            hm, tz);
        project_kernel_t<<<dim3(BB * BLOCKS_PER_B), dim3(BLOCK), 0, stream>>>(
            tz, R, T, f, c, k, p, wh, gc, gs, out);
    } else {
        project_kernel_fb<<<dim3(BB * BLOCKS_PER_B), dim3(BLOCK), 0, stream>>>(
            hm, R, T, f, c, k, p, wh, gc, gs, out);
    }
}

// Round 3
// 131.019 us; speedup vs baseline: 1.7532x; 1.1812x over previous
//
#include <hip/hip_runtime.h>
#include <hip/hip_fp16.h>

#define NCAMS 5
#define BB 4
#define JJ 15
#define JP 16                    // joints padded to 16 halves = 32 B per pixel
#define HH 128
#define WW 240
#define CXX 80
#define CYY 80
#define CZZ 20
#define NBINS 128000             // 80*80*20
#define HW (HH*WW)               // 30720
#define CUBES_ELEMS (BB*JJ*NBINS) // 7,680,000
#define BLOCK 256
#define BLOCKS_PER_B (NBINS / BLOCK) // 500
#define GRID (BB * BLOCKS_PER_B)     // 2000
#define WS_NEEDED ((size_t)NCAMS * BB * HW * JP * sizeof(__half)) // 19,660,800 B

union F4H { float4 f; __half2 h[4]; };

// ---------------------------------------------------------------------------
// Pass 1: transpose + fp16 convert (n,b,j,h,w) f32 -> (n,b,h,w,16) f16.
// Thread t produces one 16 B chunk (8 halves = 8 joints of one pixel).
// Writes perfectly coalesced float4; reads are 128 B segments per (q,j).
// ---------------------------------------------------------------------------
__global__ __launch_bounds__(BLOCK) void transpose_kernel_h(
    const float* __restrict__ hm, float4* __restrict__ tz)
{
    const int t = blockIdx.x * BLOCK + threadIdx.x;   // < 20*HW*2 = 1,228,800
    const int q = t & 1;            // low/high 8-joint group
    const int pixnb = t >> 1;
    const int nb = pixnb / HW;
    const int pix = pixnb - nb * HW;
    const float* src = hm + (size_t)nb * JJ * HW + pix;
    const int j0 = q * 8;
    F4H u;
#pragma unroll
    for (int r = 0; r < 4; ++r) {
        const int j = j0 + 2 * r;
        const float lo = src[j * HW];
        const float hi = (j + 1 < JJ) ? src[(j + 1) * HW] : 0.f;
        u.h[r] = __floats2half2_rn(lo, hi);
    }
    tz[t] = u.f;
}

// ---------------------------------------------------------------------------
// Pass 2: projection + bilinear gather from fp16 transposed layout.
// One thread per (b, voxel). Per in-bounds cam: 4 corners x 2 float4 loads
// (32 B/corner; x-adjacent corners share a 64 B line). Bilinear blend in
// v_pk_fma_f16 (error << threshold), cam-sum accumulated in fp32.
// XCD swizzle: blockIdx%8 selects a contiguous 250-tile region so each
// XCD's L2 works a compact, mostly-disjoint image footprint.
// ---------------------------------------------------------------------------
__global__ __launch_bounds__(BLOCK) void project_kernel_h(
    const float4* __restrict__ tz,  // (5,4,HW,16) halves viewed as float4[...,2]
    const float* __restrict__ R, const float* __restrict__ T,
    const float* __restrict__ f, const float* __restrict__ c,
    const float* __restrict__ k, const float* __restrict__ p,
    const float* __restrict__ wh,
    const float* __restrict__ gc, const float* __restrict__ gs,
    float* __restrict__ out)
{
    const int tile = ((blockIdx.x & 7) * (GRID / 8)) + (blockIdx.x >> 3);
    const int b = tile / BLOCKS_PER_B;
    const int m = (tile % BLOCKS_PER_B) * BLOCK + threadIdx.x;

    const int i   = m / (CYY * CZZ);
    const int rem = m - i * (CYY * CZZ);
    const int jy  = rem / CZZ;
    const int kz  = rem - jy * CZZ;

    const float gs0 = gs[0], gs1 = gs[1], gs2 = gs[2];
    const float gx = -0.5f * gs0 + (float)i  * (gs0 / (float)(CXX - 1)) + gc[b * 3 + 0];
    const float gy = -0.5f * gs1 + (float)jy * (gs1 / (float)(CYY - 1)) + gc[b * 3 + 1];
    const float gz = -0.5f * gs2 + (float)kz * (gs2 / (float)(CZZ - 1)) + gc[b * 3 + 2];

    float* gout = out + CUBES_ELEMS + ((size_t)b * NBINS + m) * 3;
    gout[0] = gx; gout[1] = gy; gout[2] = gz;

    float num[JP];
#pragma unroll
    for (int j = 0; j < JP; ++j) num[j] = 0.f;
    float den = 0.f;

    for (int n = 0; n < NCAMS; ++n) {
        const int pb = n * BB + b;                 // wave-uniform
        const float* Rp = R + pb * 9;

        const float dx = gx - T[pb * 3 + 0];
        const float dy = gy - T[pb * 3 + 1];
        const float dz = gz - T[pb * 3 + 2];

        const float xc = Rp[0] * dx + Rp[1] * dy + Rp[2] * dz;
        const float yc = Rp[3] * dx + Rp[4] * dy + Rp[5] * dz;
        const float zc = Rp[6] * dx + Rp[7] * dy + Rp[8] * dz;

        const float y0 = xc / zc;
        const float y1 = yc / zc;
        const float r2 = y0 * y0 + y1 * y1;

        const float k0 = k[pb * 3 + 0], k1 = k[pb * 3 + 1], k2 = k[pb * 3 + 2];
        const float radial = 1.f + k0 * r2 + k1 * r2 * r2 + k2 * r2 * r2 * r2;
        const float p0v = p[pb * 2 + 0], p1v = p[pb * 2 + 1];
        const float s = radial + p0v * y1 + p1v * y0;
        const float xy0 = y0 * s + r2 * p1v;
        const float xy1 = y1 * s + r2 * p0v;

        const float pixx = xy0 * f[pb * 2 + 0] + c[pb * 2 + 0];
        const float pixy = xy1 * f[pb * 2 + 1] + c[pb * 2 + 1];

        const float wv = wh[pb * 2 + 0], hv = wh[pb * 2 + 1];
        const bool inb = (pixx >= 0.f) & (pixy >= 0.f) & (pixx < wv) & (pixy < hv);
        if (!inb) continue;
        den += 1.f;

        const float maxwh = fmaxf(wv, hv);
        float pcx = fminf(fmaxf(pixx, -1.f), maxwh);
        float pcy = fminf(fmaxf(pixy, -1.f), maxwh);
        float nx = fminf(fmaxf(pcx / (wv - 1.f) * 2.f - 1.f, -1.1f), 1.1f);
        float ny = fminf(fmaxf(pcy / (hv - 1.f) * 2.f - 1.f, -1.1f), 1.1f);

        const float ix = (nx + 1.f) * 0.5f * (float)(WW - 1);
        const float iy = (ny + 1.f) * 0.5f * (float)(HH - 1);
        const float x0f = floorf(ix), y0f = floorf(iy);
        const float x1f = x0f + 1.f, y1f = y0f + 1.f;
        const float wx1 = ix - x0f, wx0 = 1.f - wx1;
        const float wy1 = iy - y0f, wy0 = 1.f - wy1;

        const float vx0 = (x0f >= 0.f && x0f < (float)WW) ? 1.f : 0.f;
        const float vx1 = (x1f >= 0.f && x1f < (float)WW) ? 1.f : 0.f;
        const float vy0 = (y0f >= 0.f && y0f < (float)HH) ? 1.f : 0.f;
        const float vy1 = (y1f >= 0.f && y1f < (float)HH) ? 1.f : 0.f;

        const float w00 = wx0 * wy0 * vx0 * vy0;
        const float w10 = wx1 * wy0 * vx1 * vy0;
        const float w01 = wx0 * wy1 * vx0 * vy1;
        const float w11 = wx1 * wy1 * vx1 * vy1;

        const int xi0 = min(max((int)x0f, 0), WW - 1);
        const int xi1 = min(max((int)x1f, 0), WW - 1);
        const int yi0 = min(max((int)y0f, 0), HH - 1);
        const int yi1 = min(max((int)y1f, 0), HH - 1);

        const float4* img = tz + (size_t)pb * HW * 2;   // 2 float4 per pixel
        const int e00 = (yi0 * WW + xi0) * 2;
        const int e10 = (yi0 * WW + xi1) * 2;
        const int e01 = (yi1 * WW + xi0) * 2;
        const int e11 = (yi1 * WW + xi1) * 2;

        // issue all 8 loads first (MLP), then blend
        F4H A0, A1, B0, B1, C0, C1, D0, D1;
        A0.f = img[e00]; A1.f = img[e00 + 1];
        B0.f = img[e10]; B1.f = img[e10 + 1];
        C0.f = img[e01]; C1.f = img[e01 + 1];
        D0.f = img[e11]; D1.f = img[e11 + 1];

        const __half2 hw00 = __float2half2_rn(w00);
        const __half2 hw10 = __float2half2_rn(w10);
        const __half2 hw01 = __float2half2_rn(w01);
        const __half2 hw11 = __float2half2_rn(w11);

#pragma unroll
        for (int r = 0; r < 4; ++r) {
            __half2 sA = __hmul2(A0.h[r], hw00);
            sA = __hfma2(B0.h[r], hw10, sA);
            sA = __hfma2(C0.h[r], hw01, sA);
            sA = __hfma2(D0.h[r], hw11, sA);
            const float2 vA = __half22float2(sA);
            num[2 * r + 0] += vA.x;
            num[2 * r + 1] += vA.y;

            __half2 sB = __hmul2(A1.h[r], hw00);
            sB = __hfma2(B1.h[r], hw10, sB);
            sB = __hfma2(C1.h[r], hw01, sB);
            sB = __hfma2(D1.h[r], hw11, sB);
            const float2 vB = __half22float2(sB);
            num[8 + 2 * r + 0] += vB.x;
            num[8 + 2 * r + 1] += vB.y;
        }
    }

    const float inv = 1.f / (den + 1e-6f);
    float* cout = out + (size_t)b * JJ * NBINS + m;
#pragma unroll
    for (int j = 0; j < JJ; ++j) {
        float v = num[j] * inv;
        v = (v != v) ? 0.f : v;
        v = fminf(fmaxf(v, 0.f), 1.f);
        cout[(size_t)j * NBINS] = v;
    }
}

// ---------------------------------------------------------------------------
// Fallback (R1 kernel): used only if ws_size < WS_NEEDED.
// ---------------------------------------------------------------------------
__global__ __launch_bounds__(BLOCK) void project_kernel_fb(
    const float* __restrict__ hm,
    const float* __restrict__ R, const float* __restrict__ T,
    const float* __restrict__ f, const float* __restrict__ c,
    const float* __restrict__ k, const float* __restrict__ p,
    const float* __restrict__ wh,
    const float* __restrict__ gc, const float* __restrict__ gs,
    float* __restrict__ out)
{
    const int b = blockIdx.x / BLOCKS_PER_B;
    const int m = (blockIdx.x % BLOCKS_PER_B) * BLOCK + threadIdx.x;
    const int i   = m / (CYY * CZZ);
    const int rem = m - i * (CYY * CZZ);
    const int jy  = rem / CZZ;
    const int kz  = rem - jy * CZZ;

    const float gs0 = gs[0], gs1 = gs[1], gs2 = gs[2];
    const float gx = -0.5f * gs0 + (float)i  * (gs0 / (float)(CXX - 1)) + gc[b * 3 + 0];
    const float gy = -0.5f * gs1 + (float)jy * (gs1 / (float)(CYY - 1)) + gc[b * 3 + 1];
    const float gz = -0.5f * gs2 + (float)kz * (gs2 / (float)(CZZ - 1)) + gc[b * 3 + 2];

    float* gout = out + CUBES_ELEMS + ((size_t)b * NBINS + m) * 3;
    gout[0] = gx; gout[1] = gy; gout[2] = gz;

    float num[JJ];
#pragma unroll
    for (int j = 0; j < JJ; ++j) num[j] = 0.f;
    float den = 0.f;

    for (int n = 0; n < NCAMS; ++n) {
        const int pb = n * BB + b;
        const float* Rp = R + pb * 9;
        const float dx = gx - T[pb * 3 + 0];
        const float dy = gy - T[pb * 3 + 1];
        const float dz = gz - T[pb * 3 + 2];
        const float xc = Rp[0] * dx + Rp[1] * dy + Rp[2] * dz;
        const float yc = Rp[3] * dx + Rp[4] * dy + Rp[5] * dz;
        const float zc = Rp[6] * dx + Rp[7] * dy + Rp[8] * dz;
        const float y0 = xc / zc;
        const float y1 = yc / zc;
        const float r2 = y0 * y0 + y1 * y1;
        const float k0 = k[pb * 3 + 0], k1 = k[pb * 3 + 1], k2 = k[pb * 3 + 2];
        const float radial = 1.f + k0 * r2 + k1 * r2 * r2 + k2 * r2 * r2 * r2;
        const float p0v = p[pb * 2 + 0], p1v = p[pb * 2 + 1];
        const float s = radial + p0v * y1 + p1v * y0;
        const float xy0 = y0 * s + r2 * p1v;
        const float xy1 = y1 * s + r2 * p0v;
        const float pixx = xy0 * f[pb * 2 + 0] + c[pb * 2 + 0];
        const float pixy = xy1 * f[pb * 2 + 1] + c[pb * 2 + 1];
        const float wv = wh[pb * 2 + 0], hv = wh[pb * 2 + 1];
        const bool inb = (pixx >= 0.f) & (pixy >= 0.f) & (pixx < wv) & (pixy < hv);
        if (!inb) continue;
        den += 1.f;
        const float maxwh = fmaxf(wv, hv);
        float pcx = fminf(fmaxf(pixx, -1.f), maxwh);
        float pcy = fminf(fmaxf(pixy, -1.f), maxwh);
        float nx = fminf(fmaxf(pcx / (wv - 1.f) * 2.f - 1.f, -1.1f), 1.1f);
        float ny = fminf(fmaxf(pcy / (hv - 1.f) * 2.f - 1.f, -1.1f), 1.1f);
        const float ix = (nx + 1.f) * 0.5f * (float)(WW - 1);
        const float iy = (ny + 1.f) * 0.5f * (float)(HH - 1);
        const float x0f = floorf(ix), y0f = floorf(iy);
        const float x1f = x0f + 1.f, y1f = y0f + 1.f;
        const float wx1 = ix - x0f, wx0 = 1.f - wx1;
        const float wy1 = iy - y0f, wy0 = 1.f - wy1;
        const float vx0 = (x0f >= 0.f && x0f < (float)WW) ? 1.f : 0.f;
        const float vx1 = (x1f >= 0.f && x1f < (float)WW) ? 1.f : 0.f;
        const float vy0 = (y0f >= 0.f && y0f < (float)HH) ? 1.f : 0.f;
        const float vy1 = (y1f >= 0.f && y1f < (float)HH) ? 1.f : 0.f;
        const float w00 = wx0 * wy0 * vx0 * vy0;
        const float w10 = wx1 * wy0 * vx1 * vy0;
        const float w01 = wx0 * wy1 * vx0 * vy1;
        const float w11 = wx1 * wy1 * vx1 * vy1;
        const int xi0 = min(max((int)x0f, 0), WW - 1);
        const int xi1 = min(max((int)x1f, 0), WW - 1);
        const int yi0 = min(max((int)y0f, 0), HH - 1);
        const int yi1 = min(max((int)y1f, 0), HH - 1);
        const int o00 = yi0 * WW + xi0;
        const int o10 = yi0 * WW + xi1;
        const int o01 = yi1 * WW + xi0;
        const int o11 = yi1 * WW + xi1;
        const float* img = hm + (size_t)pb * JJ * HW;
#pragma unroll
        for (int j = 0; j < JJ; ++j) {
            const float* pj = img + j * HW;
            num[j] += pj[o00] * w00 + pj[o10] * w10 + pj[o01] * w01 + pj[o11] * w11;
        }
    }

    const float inv = 1.f / (den + 1e-6f);
    float* cout = out + (size_t)b * JJ * NBINS + m;
#pragma unroll
    for (int j = 0; j < JJ; ++j) {
        float v = num[j] * inv;
        v = (v != v) ? 0.f : v;
        v = fminf(fmaxf(v, 0.f), 1.f);
        cout[(size_t)j * NBINS] = v;
    }
}

extern "C" void kernel_launch(void* const* d_in, const int* in_sizes, int n_in,
                              void* d_out, int out_size, void* d_ws, size_t ws_size,
                              hipStream_t stream) {
    const float* hm = (const float*)d_in[0];
    const float* R  = (const float*)d_in[1];
    const float* T  = (const float*)d_in[2];
    const float* f  = (const float*)d_in[3];
    const float* c  = (const float*)d_in[4];
    const float* k  = (const float*)d_in[5];
    const float* p  = (const float*)d_in[6];
    const float* wh = (const float*)d_in[7];
    const float* gc = (const float*)d_in[8];
    const float* gs = (const float*)d_in[9];
    float* out = (float*)d_out;

    if (ws_size >= WS_NEEDED) {
        float4* tz = (float4*)d_ws;
        // 20*HW*2 16B-chunks / 256 threads = 4800 blocks
        transpose_kernel_h<<<dim3(NCAMS * BB * HW * 2 / BLOCK), dim3(BLOCK), 0, stream>>>(
            hm, tz);
        project_kernel_h<<<dim3(GRID), dim3(BLOCK), 0, stream>>>(
            tz, R, T, f, c, k, p, wh, gc, gs, out);
    } else {
        project_kernel_fb<<<dim3(GRID), dim3(BLOCK), 0, stream>>>(
            hm, R, T, f, c, k, p, wh, gc, gs, out);
    }
}

// Round 4
// 119.900 us; speedup vs baseline: 1.9158x; 1.0927x over previous
//
#include <hip/hip_runtime.h>

#define NCAMS 5
#define BB 4
#define JJ 15
#define HH 128
#define WW 240
#define CXX 80
#define CYY 80
#define CZZ 20
#define NBINS 128000             // 80*80*20
#define HW (HH*WW)               // 30720
#define CUBES_ELEMS (BB*JJ*NBINS) // 7,680,000
#define BLOCK 256
#define BLOCKS_PER_B (NBINS / BLOCK) // 500
#define GRID (BB * BLOCKS_PER_B)     // 2000
#define WS_NEEDED ((size_t)NCAMS * BB * HW * 16)  // 9,830,400 B (u8 x16/pixel)

// ---- byte-permute / u8-dot helpers (compile-safe fallbacks) ---------------
__device__ __forceinline__ unsigned prm(unsigned a, unsigned b, unsigned s) {
#if __has_builtin(__builtin_amdgcn_perm)
    return __builtin_amdgcn_perm(a, b, s);
#else
    unsigned long long v = ((unsigned long long)a << 32) | b;
    unsigned r = 0;
#pragma unroll
    for (int i = 0; i < 4; ++i) {
        unsigned idx = (s >> (8 * i)) & 0xffu;
        unsigned byte = (idx < 8) ? (unsigned)((v >> (8 * idx)) & 0xff) : 0u;
        r |= byte << (8 * i);
    }
    return r;
#endif
}

__device__ __forceinline__ unsigned dot4u8(unsigned a, unsigned b, unsigned c) {
#if __has_builtin(__builtin_amdgcn_udot4)
    return __builtin_amdgcn_udot4(a, b, c, false);
#else
    return c + (a & 0xff) * (b & 0xff)
             + ((a >> 8) & 0xff) * ((b >> 8) & 0xff)
             + ((a >> 16) & 0xff) * ((b >> 16) & 0xff)
             + (a >> 24) * (b >> 24);
#endif
}

// ---------------------------------------------------------------------------
// Pass 1: transpose + u8 quantize (n,b,j,h,w) f32 -> (n,b,h,w,16) u8 (x255).
// One thread per pixel: 15 strided-but-lane-coalesced 4B reads, one 16B write.
// ---------------------------------------------------------------------------
__global__ __launch_bounds__(BLOCK) void transpose_kernel_u8(
    const float* __restrict__ hm, uint4* __restrict__ tz)
{
    const int t = blockIdx.x * BLOCK + threadIdx.x;   // < 5*4*HW = 614,400
    const int nb = t / HW;
    const int pix = t - nb * HW;
    const float* src = hm + (size_t)nb * JJ * HW + pix;
    unsigned w[4] = {0u, 0u, 0u, 0u};
#pragma unroll
    for (int j = 0; j < JJ; ++j) {
        const float v = src[j * HW];
        unsigned u = (unsigned)(v * 255.f + 0.5f);
        u = u > 255u ? 255u : u;
        w[j >> 2] |= u << ((j & 3) * 8);
    }
    uint4 o; o.x = w[0]; o.y = w[1]; o.z = w[2]; o.w = w[3];
    tz[t] = o;
}

// ---------------------------------------------------------------------------
// Pass 2: projection + bilinear gather from u8 layout.
// Per in-bounds cam: 4 corners x 1 dwordx4 load (16 B); per joint:
// 3x v_perm (assemble {A,B,C,D} bytes) + 1x v_dot4_u32_u8 with 8-bit weights,
// accumulated in i32 across cams. Final scale 1/(255*255*den).
// ---------------------------------------------------------------------------
__global__ __launch_bounds__(BLOCK) void project_kernel_u8(
    const uint4* __restrict__ tz,   // (5,4,HW) x 16 bytes
    const float* __restrict__ R, const float* __restrict__ T,
    const float* __restrict__ f, const float* __restrict__ c,
    const float* __restrict__ k, const float* __restrict__ p,
    const float* __restrict__ wh,
    const float* __restrict__ gc, const float* __restrict__ gs,
    float* __restrict__ out)
{
    const int tile = ((blockIdx.x & 7) * (GRID / 8)) + (blockIdx.x >> 3);
    const int b = tile / BLOCKS_PER_B;
    const int m = (tile % BLOCKS_PER_B) * BLOCK + threadIdx.x;

    const int i   = m / (CYY * CZZ);
    const int rem = m - i * (CYY * CZZ);
    const int jy  = rem / CZZ;
    const int kz  = rem - jy * CZZ;

    const float gs0 = gs[0], gs1 = gs[1], gs2 = gs[2];
    const float gx = -0.5f * gs0 + (float)i  * (gs0 / (float)(CXX - 1)) + gc[b * 3 + 0];
    const float gy = -0.5f * gs1 + (float)jy * (gs1 / (float)(CYY - 1)) + gc[b * 3 + 1];
    const float gz = -0.5f * gs2 + (float)kz * (gs2 / (float)(CZZ - 1)) + gc[b * 3 + 2];

    float* gout = out + CUBES_ELEMS + ((size_t)b * NBINS + m) * 3;
    gout[0] = gx; gout[1] = gy; gout[2] = gz;

    unsigned acc[JJ];
#pragma unroll
    for (int j = 0; j < JJ; ++j) acc[j] = 0u;
    float den = 0.f;

    for (int n = 0; n < NCAMS; ++n) {
        const int pb = n * BB + b;                 // wave-uniform
        const float* Rp = R + pb * 9;

        const float dx = gx - T[pb * 3 + 0];
        const float dy = gy - T[pb * 3 + 1];
        const float dz = gz - T[pb * 3 + 2];

        const float xc = Rp[0] * dx + Rp[1] * dy + Rp[2] * dz;
        const float yc = Rp[3] * dx + Rp[4] * dy + Rp[5] * dz;
        const float zc = Rp[6] * dx + Rp[7] * dy + Rp[8] * dz;

        const float y0 = xc / zc;
        const float y1 = yc / zc;
        const float r2 = y0 * y0 + y1 * y1;

        const float k0 = k[pb * 3 + 0], k1 = k[pb * 3 + 1], k2 = k[pb * 3 + 2];
        const float radial = 1.f + k0 * r2 + k1 * r2 * r2 + k2 * r2 * r2 * r2;
        const float p0v = p[pb * 2 + 0], p1v = p[pb * 2 + 1];
        const float s = radial + p0v * y1 + p1v * y0;
        const float xy0 = y0 * s + r2 * p1v;
        const float xy1 = y1 * s + r2 * p0v;

        const float pixx = xy0 * f[pb * 2 + 0] + c[pb * 2 + 0];
        const float pixy = xy1 * f[pb * 2 + 1] + c[pb * 2 + 1];

        const float wv = wh[pb * 2 + 0], hv = wh[pb * 2 + 1];
        const bool inb = (pixx >= 0.f) & (pixy >= 0.f) & (pixx < wv) & (pixy < hv);
        if (!inb) continue;
        den += 1.f;

        const float maxwh = fmaxf(wv, hv);
        float pcx = fminf(fmaxf(pixx, -1.f), maxwh);
        float pcy = fminf(fmaxf(pixy, -1.f), maxwh);
        float nx = fminf(fmaxf(pcx / (wv - 1.f) * 2.f - 1.f, -1.1f), 1.1f);
        float ny = fminf(fmaxf(pcy / (hv - 1.f) * 2.f - 1.f, -1.1f), 1.1f);

        const float ix = (nx + 1.f) * 0.5f * (float)(WW - 1);
        const float iy = (ny + 1.f) * 0.5f * (float)(HH - 1);
        const float x0f = floorf(ix), y0f = floorf(iy);
        const float x1f = x0f + 1.f, y1f = y0f + 1.f;
        const float wx1 = ix - x0f, wx0 = 1.f - wx1;
        const float wy1 = iy - y0f, wy0 = 1.f - wy1;

        const float vx0 = (x0f >= 0.f && x0f < (float)WW) ? 1.f : 0.f;
        const float vx1 = (x1f >= 0.f && x1f < (float)WW) ? 1.f : 0.f;
        const float vy0 = (y0f >= 0.f && y0f < (float)HH) ? 1.f : 0.f;
        const float vy1 = (y1f >= 0.f && y1f < (float)HH) ? 1.f : 0.f;

        const float w00 = wx0 * wy0 * vx0 * vy0;
        const float w10 = wx1 * wy0 * vx1 * vy0;
        const float w01 = wx0 * wy1 * vx0 * vy1;
        const float w11 = wx1 * wy1 * vx1 * vy1;

        const int xi0 = min(max((int)x0f, 0), WW - 1);
        const int xi1 = min(max((int)x1f, 0), WW - 1);
        const int yi0 = min(max((int)y0f, 0), HH - 1);
        const int yi1 = min(max((int)y1f, 0), HH - 1);

        const uint4* img = tz + (size_t)pb * HW;
        // issue all 4 corner loads first (MLP)
        const uint4 A = img[yi0 * WW + xi0];
        const uint4 Bc = img[yi0 * WW + xi1];
        const uint4 Cc = img[yi1 * WW + xi0];
        const uint4 D = img[yi1 * WW + xi1];

        // 8-bit weights, packed to match byte lanes {A,B,C,D}
        const unsigned u00 = (unsigned)(w00 * 255.f + 0.5f);
        const unsigned u10 = (unsigned)(w10 * 255.f + 0.5f);
        const unsigned u01 = (unsigned)(w01 * 255.f + 0.5f);
        const unsigned u11 = (unsigned)(w11 * 255.f + 0.5f);
        const unsigned wp = u00 | (u10 << 8) | (u01 << 16) | (u11 << 24);

        const unsigned Aa[4] = {A.x,  A.y,  A.z,  A.w};
        const unsigned Ba[4] = {Bc.x, Bc.y, Bc.z, Bc.w};
        const unsigned Ca[4] = {Cc.x, Cc.y, Cc.z, Cc.w};
        const unsigned Da[4] = {D.x,  D.y,  D.z,  D.w};

#pragma unroll
        for (int j = 0; j < JJ; ++j) {
            const int d = j >> 2;
            const unsigned bj = (unsigned)(j & 3);
            // perm: s0 bytes are indices 4..7, s1 bytes are 0..3; 0x0c -> 0x00
            const unsigned selAB = 0x0c0c0000u | (bj << 8) | (bj + 4u);
            const unsigned mAB = prm(Aa[d], Ba[d], selAB);   // {A_j, B_j, 0, 0}
            const unsigned mCD = prm(Ca[d], Da[d], selAB);   // {C_j, D_j, 0, 0}
            const unsigned bytes = prm(mAB, mCD, 0x01000504u); // {A_j,B_j,C_j,D_j}
            acc[j] = dot4u8(bytes, wp, acc[j]);
        }
    }

    const float inv = 1.f / ((den + 1e-6f) * (255.f * 255.f));
    float* cout = out + (size_t)b * JJ * NBINS + m;
#pragma unroll
    for (int j = 0; j < JJ; ++j) {
        float v = (float)acc[j] * inv;
        v = fminf(fmaxf(v, 0.f), 1.f);
        cout[(size_t)j * NBINS] = v;
    }
}

// ---------------------------------------------------------------------------
// Fallback (R1 kernel): used only if ws_size < WS_NEEDED.
// ---------------------------------------------------------------------------
__global__ __launch_bounds__(BLOCK) void project_kernel_fb(
    const float* __restrict__ hm,
    const float* __restrict__ R, const float* __restrict__ T,
    const float* __restrict__ f, const float* __restrict__ c,
    const float* __restrict__ k, const float* __restrict__ p,
    const float* __restrict__ wh,
    const float* __restrict__ gc, const float* __restrict__ gs,
    float* __restrict__ out)
{
    const int b = blockIdx.x / BLOCKS_PER_B;
    const int m = (blockIdx.x % BLOCKS_PER_B) * BLOCK + threadIdx.x;
    const int i   = m / (CYY * CZZ);
    const int rem = m - i * (CYY * CZZ);
    const int jy  = rem / CZZ;
    const int kz  = rem - jy * CZZ;

    const float gs0 = gs[0], gs1 = gs[1], gs2 = gs[2];
    const float gx = -0.5f * gs0 + (float)i  * (gs0 / (float)(CXX - 1)) + gc[b * 3 + 0];
    const float gy = -0.5f * gs1 + (float)jy * (gs1 / (float)(CYY - 1)) + gc[b * 3 + 1];
    const float gz = -0.5f * gs2 + (float)kz * (gs2 / (float)(CZZ - 1)) + gc[b * 3 + 2];

    float* gout = out + CUBES_ELEMS + ((size_t)b * NBINS + m) * 3;
    gout[0] = gx; gout[1] = gy; gout[2] = gz;

    float num[JJ];
#pragma unroll
    for (int j = 0; j < JJ; ++j) num[j] = 0.f;
    float den = 0.f;

    for (int n = 0; n < NCAMS; ++n) {
        const int pb = n * BB + b;
        const float* Rp = R + pb * 9;
        const float dx = gx - T[pb * 3 + 0];
        const float dy = gy - T[pb * 3 + 1];
        const float dz = gz - T[pb * 3 + 2];
        const float xc = Rp[0] * dx + Rp[1] * dy + Rp[2] * dz;
        const float yc = Rp[3] * dx + Rp[4] * dy + Rp[5] * dz;
        const float zc = Rp[6] * dx + Rp[7] * dy + Rp[8] * dz;
        const float y0 = xc / zc;
        const float y1 = yc / zc;
        const float r2 = y0 * y0 + y1 * y1;
        const float k0 = k[pb * 3 + 0], k1 = k[pb * 3 + 1], k2 = k[pb * 3 + 2];
        const float radial = 1.f + k0 * r2 + k1 * r2 * r2 + k2 * r2 * r2 * r2;
        const float p0v = p[pb * 2 + 0], p1v = p[pb * 2 + 1];
        const float s = radial + p0v * y1 + p1v * y0;
        const float xy0 = y0 * s + r2 * p1v;
        const float xy1 = y1 * s + r2 * p0v;
        const float pixx = xy0 * f[pb * 2 + 0] + c[pb * 2 + 0];
        const float pixy = xy1 * f[pb * 2 + 1] + c[pb * 2 + 1];
        const float wv = wh[pb * 2 + 0], hv = wh[pb * 2 + 1];
        const bool inb = (pixx >= 0.f) & (pixy >= 0.f) & (pixx < wv) & (pixy < hv);
        if (!inb) continue;
        den += 1.f;
        const float maxwh = fmaxf(wv, hv);
        float pcx = fminf(fmaxf(pixx, -1.f), maxwh);
        float pcy = fminf(fmaxf(pixy, -1.f), maxwh);
        float nx = fminf(fmaxf(pcx / (wv - 1.f) * 2.f - 1.f, -1.1f), 1.1f);
        float ny = fminf(fmaxf(pcy / (hv - 1.f) * 2.f - 1.f, -1.1f), 1.1f);
        const float ix = (nx + 1.f) * 0.5f * (float)(WW - 1);
        const float iy = (ny + 1.f) * 0.5f * (float)(HH - 1);
        const float x0f = floorf(ix), y0f = floorf(iy);
        const float x1f = x0f + 1.f, y1f = y0f + 1.f;
        const float wx1 = ix - x0f, wx0 = 1.f - wx1;
        const float wy1 = iy - y0f, wy0 = 1.f - wy1;
        const float vx0 = (x0f >= 0.f && x0f < (float)WW) ? 1.f : 0.f;
        const float vx1 = (x1f >= 0.f && x1f < (float)WW) ? 1.f : 0.f;
        const float vy0 = (y0f >= 0.f && y0f < (float)HH) ? 1.f : 0.f;
        const float vy1 = (y1f >= 0.f && y1f < (float)HH) ? 1.f : 0.f;
        const float w00 = wx0 * wy0 * vx0 * vy0;
        const float w10 = wx1 * wy0 * vx1 * vy0;
        const float w01 = wx0 * wy1 * vx0 * vy1;
        const float w11 = wx1 * wy1 * vx1 * vy1;
        const int xi0 = min(max((int)x0f, 0), WW - 1);
        const int xi1 = min(max((int)x1f, 0), WW - 1);
        const int yi0 = min(max((int)y0f, 0), HH - 1);
        const int yi1 = min(max((int)y1f, 0), HH - 1);
        const int o00 = yi0 * WW + xi0;
        const int o10 = yi0 * WW + xi1;
        const int o01 = yi1 * WW + xi0;
        const int o11 = yi1 * WW + xi1;
        const float* img = hm + (size_t)pb * JJ * HW;
#pragma unroll
        for (int j = 0; j < JJ; ++j) {
            const float* pj = img + j * HW;
            num[j] += pj[o00] * w00 + pj[o10] * w10 + pj[o01] * w01 + pj[o11] * w11;
        }
    }

    const float inv = 1.f / (den + 1e-6f);
    float* cout = out + (size_t)b * JJ * NBINS + m;
#pragma unroll
    for (int j = 0; j < JJ; ++j) {
        float v = num[j] * inv;
        v = (v != v) ? 0.f : v;
        v = fminf(fmaxf(v, 0.f), 1.f);
        cout[(size_t)j * NBINS] = v;
    }
}

extern "C" void kernel_launch(void* const* d_in, const int* in_sizes, int n_in,
                              void* d_out, int out_size, void* d_ws, size_t ws_size,
                              hipStream_t stream) {
    const float* hm = (const float*)d_in[0];
    const float* R  = (const float*)d_in[1];
    const float* T  = (const float*)d_in[2];
    const float* f  = (const float*)d_in[3];
    const float* c  = (const float*)d_in[4];
    const float* k  = (const float*)d_in[5];
    const float* p  = (const float*)d_in[6];
    const float* wh = (const float*)d_in[7];
    const float* gc = (const float*)d_in[8];
    const float* gs = (const float*)d_in[9];
    float* out = (float*)d_out;

    if (ws_size >= WS_NEEDED) {
        uint4* tz = (uint4*)d_ws;
        transpose_kernel_u8<<<dim3(NCAMS * BB * HW / BLOCK), dim3(BLOCK), 0, stream>>>(
            hm, tz);
        project_kernel_u8<<<dim3(GRID), dim3(BLOCK), 0, stream>>>(
            tz, R, T, f, c, k, p, wh, gc, gs, out);
    } else {
        project_kernel_fb<<<dim3(GRID), dim3(BLOCK), 0, stream>>>(
            hm, R, T, f, c, k, p, wh, gc, gs, out);
    }
}